// Round 15
// baseline (385.171 us; speedup 1.0000x reference)
//
#include <hip/hip_runtime.h>

#define N_NODES 50000
#define NP      50016                      // panel rows incl. sentinel row 50000
#define N_EDGES 600000
#define EDGE_CAP 750016                    // padded edge capacity (E + 3N + pad)
#define SENT    50000                      // sentinel src for pads (colw=0)
#define XS_STRIDE 132                      // LDS row stride: 128 + 4 pad
#define PANEL ((size_t)NP * 16)            // floats per 16-col feature panel
#define SORT_CAP 48                        // LDS sort capacity (Poisson(12) max ~35)
#define SORT_STRIDE 50                     // u16 stride: 100B -> bank stride 25, conflict-free

// ---------------- graph build ----------------

__global__ void count_edges(const int* __restrict__ dst, int* __restrict__ cnt) {
    int e = blockIdx.x * blockDim.x + threadIdx.x;
    if (e < N_EDGES) atomicAdd(&cnt[dst[e]], 1);
}

// start[v] = atomicAdd(total, padded_c) (uniform-address atomic -> wave-coalesced).
// Row PLACEMENT is nondeterministic across replays, but row CONTENT is
// canonicalized by sort_rows, so no float math depends on placement.
__global__ void reserve_rows(const int* __restrict__ cnt, int* __restrict__ start,
                             int* __restrict__ cnt_pad, int* __restrict__ total,
                             float* __restrict__ dinv, unsigned short* __restrict__ col16) {
    int i = blockIdx.x * blockDim.x + threadIdx.x;
    if (i < N_NODES) {
        int c = cnt[i];
        int pc = (c + 3) & ~3;
        int s = atomicAdd(total, pc);
        start[i] = s;
        cnt_pad[i] = pc;
        dinv[i] = 1.0f / sqrtf((float)(c + 1));   // +1 self-loop
        for (int p = s + c; p < s + pc; ++p) col16[p] = (unsigned short)SENT;
        if (i == 0) dinv[SENT] = 0.f;             // pads contribute exactly 0
    }
}

__global__ void csr_fill(const int* __restrict__ srcArr, const int* __restrict__ dstArr,
                         const int* __restrict__ start, int* __restrict__ fill,
                         unsigned short* __restrict__ col16) {
    int e = blockIdx.x * blockDim.x + threadIdx.x;
    if (e < N_EDGES) {
        int d = dstArr[e];
        int pos = start[d] + atomicAdd(&fill[d], 1);
        col16[pos] = (unsigned short)srcArr[e];
    }
}

// DETERMINISM: canonical per-row order (ascending src) -> bitwise-stable sums.
// LDS insertion sort (r13: moved off global; 63us -> below top-5).
__global__ __launch_bounds__(64) void sort_rows(
        const int* __restrict__ start, const int* __restrict__ cnt,
        const int* __restrict__ cnt_pad, const float* __restrict__ dinv,
        unsigned short* __restrict__ col16, float* __restrict__ colw) {
    __shared__ unsigned short buf[64 * SORT_STRIDE];
    int lane = threadIdx.x;
    int v = blockIdx.x * 64 + lane;
    if (v >= N_NODES) return;
    int beg = start[v], c = cnt[v];
    unsigned short* row = &buf[lane * SORT_STRIDE];
    if (c <= SORT_CAP) {
        for (int i = 0; i < c; ++i) row[i] = col16[beg + i];
        for (int i = 1; i < c; ++i) {
            unsigned short key = row[i];
            int j = i - 1;
            while (j >= 0 && row[j] > key) { row[j + 1] = row[j]; --j; }
            row[j + 1] = key;
        }
        for (int i = 0; i < c; ++i) col16[beg + i] = row[i];
    } else {   // unconditional-correctness fallback (not expected to fire)
        for (int i = 1; i < c; ++i) {
            unsigned short key = col16[beg + i];
            int j = i - 1;
            while (j >= 0 && col16[beg + j] > key) {
                col16[beg + j + 1] = col16[beg + j];
                --j;
            }
            col16[beg + j + 1] = key;
        }
    }
    int pc = cnt_pad[v];
    for (int p = beg; p < beg + pc; ++p) colw[p] = dinv[col16[p]];
}

// ---------------- dense GEMM [N,128]@[128,128] -> panel output ----------------
// block = 256 threads, tile = 64 rows x 128 cols, micro-tile 4x8.
// r13 PMC: 45.5us, VALUBusy 25% vs 10.4us FMA floor -> latency-stalled on W
// loads (8 float4 issued immediately before use each k-step). Fix: 2-phase
// register double-buffer prefetch (named w0/w1 for static indexing) so each
// 256-cyc FMA block hides the next slice's L1/L2 latency.
// MODE 0: input row-major x. MODE 1: input panel layout.

template <int MODE>
__global__ __launch_bounds__(256) void gemm128_t(const float* __restrict__ X,
                                                 const float* __restrict__ W,
                                                 float* __restrict__ T) {
    __shared__ float xs[64 * XS_STRIDE];
    int tid = threadIdx.x;
    int row0 = blockIdx.x * 64;

    #pragma unroll
    for (int i = 0; i < 8; ++i) {
        int fi = tid + i * 256;
        int r  = fi >> 5;
        int c4 = (fi & 31) << 2;
        float4 v = make_float4(0.f, 0.f, 0.f, 0.f);
        int rg = row0 + r;
        if (rg < N_NODES) {
            if (MODE == 0) {
                v = *(const float4*)&X[(size_t)rg * 128 + c4];
            } else {
                int f = c4 >> 4, off = c4 & 15;
                v = *(const float4*)&X[(size_t)f * PANEL + (size_t)rg * 16 + off];
            }
        }
        float* p = &xs[r * XS_STRIDE + c4];
        p[0] = v.x; p[1] = v.y; p[2] = v.z; p[3] = v.w;
    }
    __syncthreads();

    int cg = tid & 15, rg = tid >> 4;
    int c0 = cg * 8, r0 = rg * 4;
    float acc[4][8];
    #pragma unroll
    for (int i = 0; i < 4; ++i)
        #pragma unroll
        for (int j = 0; j < 8; ++j) acc[i][j] = 0.f;

    float4 w0[8], w1[8];
    #pragma unroll
    for (int kk = 0; kk < 4; ++kk) {
        w0[2 * kk]     = *(const float4*)&W[kk * 128 + c0];
        w0[2 * kk + 1] = *(const float4*)&W[kk * 128 + c0 + 4];
    }

    #define FMA_BLOCK(WREG, KOFF)                                              \
        {                                                                      \
            float4 a[4];                                                       \
            _Pragma("unroll")                                                  \
            for (int i = 0; i < 4; ++i)                                        \
                a[i] = *(const float4*)&xs[(r0 + i) * XS_STRIDE + (KOFF)];     \
            _Pragma("unroll")                                                  \
            for (int kk = 0; kk < 4; ++kk) {                                   \
                float4 blo = WREG[2 * kk], bhi = WREG[2 * kk + 1];             \
                _Pragma("unroll")                                              \
                for (int i = 0; i < 4; ++i) {                                  \
                    float av = (kk == 0) ? a[i].x : (kk == 1) ? a[i].y         \
                             : (kk == 2) ? a[i].z : a[i].w;                    \
                    acc[i][0] = fmaf(av, blo.x, acc[i][0]);                    \
                    acc[i][1] = fmaf(av, blo.y, acc[i][1]);                    \
                    acc[i][2] = fmaf(av, blo.z, acc[i][2]);                    \
                    acc[i][3] = fmaf(av, blo.w, acc[i][3]);                    \
                    acc[i][4] = fmaf(av, bhi.x, acc[i][4]);                    \
                    acc[i][5] = fmaf(av, bhi.y, acc[i][5]);                    \
                    acc[i][6] = fmaf(av, bhi.z, acc[i][6]);                    \
                    acc[i][7] = fmaf(av, bhi.w, acc[i][7]);                    \
                }                                                              \
            }                                                                  \
        }

    for (int k0 = 0; k0 < 128; k0 += 8) {
        // prefetch phase-B W (k0+4..k0+7) -> in flight during phase-A FMAs
        #pragma unroll
        for (int kk = 0; kk < 4; ++kk) {
            w1[2 * kk]     = *(const float4*)&W[(k0 + 4 + kk) * 128 + c0];
            w1[2 * kk + 1] = *(const float4*)&W[(k0 + 4 + kk) * 128 + c0 + 4];
        }
        FMA_BLOCK(w0, k0)
        // prefetch phase-A W for k0+8 (harmless re-load of k=0 on last iter)
        int kp = (k0 + 8 < 128) ? (k0 + 8) : 0;
        #pragma unroll
        for (int kk = 0; kk < 4; ++kk) {
            w0[2 * kk]     = *(const float4*)&W[(kp + kk) * 128 + c0];
            w0[2 * kk + 1] = *(const float4*)&W[(kp + kk) * 128 + c0 + 4];
        }
        FMA_BLOCK(w1, k0 + 4)
    }
    #undef FMA_BLOCK

    int f = c0 >> 4, off = c0 & 15;
    #pragma unroll
    for (int i = 0; i < 4; ++i) {
        int r = row0 + r0 + i;
        if (r < N_NODES) {
            float* base = &T[(size_t)f * PANEL + (size_t)r * 16 + off];
            *(float4*)&base[0] = make_float4(acc[i][0], acc[i][1], acc[i][2], acc[i][3]);
            *(float4*)&base[4] = make_float4(acc[i][4], acc[i][5], acc[i][6], acc[i][7]);
        }
    }
}

// ---------------- aggregation over panels ----------------
// blockIdx % 8 = feature panel f (-> XCD f round-robin; 3.2MB panel ~L2-resident).
// block = 256 = 64 nodes x 4 lanes (float4 per lane). Edges: u16 src (ushort4)
// + sequential f32 colw (float4), both broadcast across a node's 4 lanes.
// Rows sorted + padded to x4 with colw=0 -> branch-free deterministic loop.

__global__ __launch_bounds__(256) void gcn_aggregate_pn(
        const float* __restrict__ T, const int* __restrict__ start,
        const int* __restrict__ cnt_pad, const unsigned short* __restrict__ col16,
        const float* __restrict__ colw, const float* __restrict__ dinv,
        const float* __restrict__ bias, float* __restrict__ outp) {
    int f  = blockIdx.x & 7;
    int nb = blockIdx.x >> 3;
    int tid = threadIdx.x;
    int v = nb * 64 + (tid >> 2);
    if (v >= N_NODES) return;
    int j4 = (tid & 3) << 2;

    const float* __restrict__ Tp = T + (size_t)f * PANEL;
    float dv = dinv[v];
    const float4 tv = *(const float4*)&Tp[(size_t)v * 16 + j4];
    float4 acc = make_float4(dv * tv.x, dv * tv.y, dv * tv.z, dv * tv.w);

    int beg = start[v], end = beg + cnt_pad[v];      // multiple of 4, aligned
    for (int e = beg; e < end; e += 4) {
        ushort4 c4v = *(const ushort4*)&col16[e];
        float4  w4  = *(const float4*)&colw[e];
        int s0 = c4v.x, s1 = c4v.y, s2 = c4v.z, s3 = c4v.w;
        const float4 t0 = *(const float4*)&Tp[(size_t)s0 * 16 + j4];
        const float4 t1 = *(const float4*)&Tp[(size_t)s1 * 16 + j4];
        const float4 t2 = *(const float4*)&Tp[(size_t)s2 * 16 + j4];
        const float4 t3 = *(const float4*)&Tp[(size_t)s3 * 16 + j4];
        acc.x = fmaf(w4.x, t0.x, fmaf(w4.y, t1.x, fmaf(w4.z, t2.x, fmaf(w4.w, t3.x, acc.x))));
        acc.y = fmaf(w4.x, t0.y, fmaf(w4.y, t1.y, fmaf(w4.z, t2.y, fmaf(w4.w, t3.y, acc.y))));
        acc.z = fmaf(w4.x, t0.z, fmaf(w4.y, t1.z, fmaf(w4.z, t2.z, fmaf(w4.w, t3.z, acc.z))));
        acc.w = fmaf(w4.x, t0.w, fmaf(w4.y, t1.w, fmaf(w4.z, t2.w, fmaf(w4.w, t3.w, acc.w))));
    }

    const float4 b4 = *(const float4*)&bias[f * 16 + j4];
    float4 r;
    r.x = fmaxf(fmaf(dv, acc.x, b4.x), 0.f);
    r.y = fmaxf(fmaf(dv, acc.y, b4.y), 0.f);
    r.z = fmaxf(fmaf(dv, acc.z, b4.z), 0.f);
    r.w = fmaxf(fmaf(dv, acc.w, b4.w), 0.f);
    *(float4*)&outp[(size_t)f * PANEL + (size_t)v * 16 + j4] = r;
}

// ---------------- final linear [N,128]@[128,32] + bias, panel input ----------------

__global__ __launch_bounds__(256) void gemm_final_pn(
        const float* __restrict__ Hp, const float* __restrict__ Wl,
        const float* __restrict__ bl, float* __restrict__ out32) {
    __shared__ float sh[8 * 128];
    int tid = threadIdx.x;
    int g = tid >> 5, lane = tid & 31;
    int v = blockIdx.x * 8 + g;          // grid = 6250 exactly
    int c4 = lane << 2;
    int f = c4 >> 4, off = c4 & 15;
    const float4 hv = *(const float4*)&Hp[(size_t)f * PANEL + (size_t)v * 16 + off];
    *(float4*)&sh[g * 128 + c4] = hv;
    __syncthreads();

    float o = bl[lane];
    const float* hrow = &sh[g * 128];
    #pragma unroll 8
    for (int j = 0; j < 128; ++j)
        o = fmaf(hrow[j], Wl[j * 32 + lane], o);
    out32[(size_t)v * 32 + lane] = o;
}

// ---------------- launch ----------------

extern "C" void kernel_launch(void* const* d_in, const int* in_sizes, int n_in,
                              void* d_out, int out_size, void* d_ws, size_t ws_size,
                              hipStream_t stream) {
    const float* x      = (const float*)d_in[0];
    const int*   ei     = (const int*)d_in[1];
    const int*   srcArr = ei;
    const int*   dstArr = ei + N_EDGES;
    const float* W1 = (const float*)d_in[2];
    const float* b1 = (const float*)d_in[3];
    const float* W2 = (const float*)d_in[4];
    const float* b2 = (const float*)d_in[5];
    const float* W3 = (const float*)d_in[6];
    const float* b3 = (const float*)d_in[7];
    const float* Wl = (const float*)d_in[8];
    const float* bl = (const float*)d_in[9];
    float* out = (float*)d_out;

    // workspace layout (~56.7 MB)
    float* bufA   = (float*)d_ws;                             // 8*PANEL
    float* bufB   = bufA + 8 * PANEL;                         // 8*PANEL
    unsigned short* col16 = (unsigned short*)(bufB + 8 * PANEL); // EDGE_CAP u16
    float* colw   = (float*)(col16 + EDGE_CAP);               // EDGE_CAP f32
    float* dinv   = colw + EDGE_CAP;                          // N+1
    int*   cnt    = (int*)(dinv + N_NODES + 1);               // N   <- memset base
    int*   fill   = cnt + N_NODES;                            // N
    int*   total  = fill + N_NODES;                           // 1   <- memset end
    int*   start  = total + 1;                                // N
    int*   cnt_pad= start + N_NODES;                          // N

    hipMemsetAsync(cnt, 0, (size_t)(2 * N_NODES + 1) * sizeof(int), stream);
    count_edges <<<(N_EDGES + 255) / 256, 256, 0, stream>>>(dstArr, cnt);
    reserve_rows<<<(N_NODES + 255) / 256, 256, 0, stream>>>(cnt, start, cnt_pad, total, dinv, col16);
    csr_fill    <<<(N_EDGES + 255) / 256, 256, 0, stream>>>(srcArr, dstArr, start, fill, col16);
    sort_rows   <<<(N_NODES + 63) / 64, 64, 0, stream>>>(start, cnt, cnt_pad, dinv, col16, colw);

    const int GEMM_GRID = (N_NODES + 63) / 64;           // 782
    const int AGG_GRID  = ((N_NODES + 63) / 64) * 8;     // 6256: blockIdx%8 = panel/XCD

    gemm128_t<0><<<GEMM_GRID, 256, 0, stream>>>(x, W1, bufA);
    gcn_aggregate_pn<<<AGG_GRID, 256, 0, stream>>>(bufA, start, cnt_pad, col16, colw, dinv, b1, bufB);
    gemm128_t<1><<<GEMM_GRID, 256, 0, stream>>>(bufB, W2, bufA);
    gcn_aggregate_pn<<<AGG_GRID, 256, 0, stream>>>(bufA, start, cnt_pad, col16, colw, dinv, b2, bufB);
    gemm128_t<1><<<GEMM_GRID, 256, 0, stream>>>(bufB, W3, bufA);
    gcn_aggregate_pn<<<AGG_GRID, 256, 0, stream>>>(bufA, start, cnt_pad, col16, colw, dinv, b3, bufB);
    gemm_final_pn<<<N_NODES / 8, 256, 0, stream>>>(bufB, Wl, bl, out);
}